// Round 1
// baseline (1087.588 us; speedup 1.0000x reference)
//
#include <hip/hip_runtime.h>
#include <math.h>

#define N_TOK 65536
#define H_DIM 1024

typedef __attribute__((ext_vector_type(8))) short bf16x8;
typedef __attribute__((ext_vector_type(4))) float f32x4;

// ---------------- ws layout (bytes) ----------------
static const size_t WS_CNT   = 0;                       // int[4]
static const size_t WS_OFFS  = 64;                      // int[4]
static const size_t WS_PERM  = 128;                     // int[3*N_TOK] = 768KB
static const size_t WS_WT13  = 1ull << 20;              // bf16 [3][2048][1024] = 12MB (W1/W3 16-col interleave, k-chunk pre-swizzled)
static const size_t WS_WT2   = WS_WT13 + 12582912ull;   // bf16 [3][1024][1024] = 6MB (k-chunk pre-swizzled)
static const size_t WS_XB    = 20ull << 20;             // bf16 [N][H] = 128MB (linear)
static const size_t WS_INNER = WS_XB + 134217728ull;    // bf16 [N][H] = 128MB (linear, bucket-compacted)

static __device__ __forceinline__ unsigned short f2bf(float f) {
  union { float f; unsigned int u; } v; v.f = f;
  unsigned int r = v.u + 0x7fffu + ((v.u >> 16) & 1u);
  return (unsigned short)(r >> 16);
}

// 16B-per-lane async global->LDS. LDS dest = wave-uniform base + lane*16 (linear).
static __device__ __forceinline__ void gload16(const void* g, void* l) {
  __builtin_amdgcn_global_load_lds(
      (const __attribute__((address_space(1))) unsigned int*)g,
      (__attribute__((address_space(3))) unsigned int*)l, 16, 0, 0);
}

static __device__ __forceinline__ void bar() {
  asm volatile("" ::: "memory");
  __builtin_amdgcn_s_barrier();
  asm volatile("" ::: "memory");
}

__global__ void init_kernel(int* cnt) {
  if (threadIdx.x < 4) cnt[threadIdx.x] = 0;
}

// one wave per row: 3 gate logits + gumbel argmax + x->bf16 conversion.
__global__ __launch_bounds__(1024) void gate_kernel(
    const float* __restrict__ x, const float* __restrict__ Wg,
    const float* __restrict__ bg, const float* __restrict__ gu,
    unsigned short* __restrict__ xb, int* __restrict__ cnt,
    int* __restrict__ perm)
{
  __shared__ float wg[3072];
  __shared__ int bexp[16];
  for (int i = threadIdx.x; i < 3072; i += 1024) wg[i] = Wg[i];
  __syncthreads();
  const int wave = threadIdx.x >> 6;
  const int lane = threadIdx.x & 63;
  const int n0 = blockIdx.x * 16;
  const int n = n0 + wave;
  const float4* xrow = (const float4*)(x + (size_t)n * H_DIM);
  unsigned short* xbrow = xb + (size_t)n * H_DIM;
  float s0 = 0.f, s1 = 0.f, s2 = 0.f;
#pragma unroll
  for (int j = 0; j < 4; j++) {
    float4 v = xrow[j * 64 + lane];
    int d0 = (j * 64 + lane) * 4;
    const float* w = &wg[d0 * 3];
    s0 += v.x * w[0] + v.y * w[3] + v.z * w[6] + v.w * w[9];
    s1 += v.x * w[1] + v.y * w[4] + v.z * w[7] + v.w * w[10];
    s2 += v.x * w[2] + v.y * w[5] + v.z * w[8] + v.w * w[11];
    uint2 p;
    p.x = (unsigned)f2bf(v.x) | ((unsigned)f2bf(v.y) << 16);
    p.y = (unsigned)f2bf(v.z) | ((unsigned)f2bf(v.w) << 16);
    ((uint2*)xbrow)[j * 64 + lane] = p;
  }
#pragma unroll
  for (int o = 32; o; o >>= 1) {
    s0 += __shfl_xor(s0, o);
    s1 += __shfl_xor(s1, o);
    s2 += __shfl_xor(s2, o);
  }
  if (lane == 0) {
    const float* u = gu + (size_t)n * 3;
    float l[3] = { s0 + bg[0], s1 + bg[1], s2 + bg[2] };
    int best = 0; float bs = -1e30f;
#pragma unroll
    for (int e = 0; e < 3; e++) {
      float uc = fminf(fmaxf(u[e], 1e-6f), 1.f - 1e-6f);
      float g = -logf(-logf(uc));
      float s = l[e] + g;
      if (s > bs) { bs = s; best = e; }   // strict > == first-max (jnp.argmax)
    }
    bexp[wave] = best;
  }
  __syncthreads();
  if (threadIdx.x == 0) {
    int lc[3] = {0, 0, 0};
    int lpos[16];
    for (int w = 0; w < 16; w++) lpos[w] = lc[bexp[w]]++;
    int lbase[3];
    for (int e = 0; e < 3; e++)
      lbase[e] = lc[e] ? atomicAdd(&cnt[e], lc[e]) : 0;
    for (int w = 0; w < 16; w++) {
      int e = bexp[w];
      perm[e * N_TOK + lbase[e] + lpos[w]] = n0 + w;
    }
  }
}

__global__ void offs_kernel(const int* __restrict__ cnt, int* __restrict__ offs) {
  offs[0] = 0; offs[1] = cnt[0]; offs[2] = cnt[0] + cnt[1]; offs[3] = N_TOK;
}

// W[e][d][h] fp32 -> bf16, transposed to [row][k], k pre-swizzled in 16B chunks
// (stored[row][kb*64 + c*8 + i] = logical[row][kb*64 + (c ^ (row&7))*8 + i]) so
// linear global_load_lds produces the XOR-swizzled LDS image.
// W1/W3 additionally interleave into wt13: 16-col groups alternate W1/W3.
__global__ __launch_bounds__(256) void wcvt_kernel(
    const float* __restrict__ W1, const float* __restrict__ W3,
    const float* __restrict__ W2,
    unsigned short* __restrict__ wt13, unsigned short* __restrict__ wt2)
{
  const int z = blockIdx.z, e = z / 3, m = z % 3;
  const float* src = (m == 0 ? W1 : (m == 1 ? W3 : W2)) + ((size_t)e << 20);
  __shared__ float t[32][33];
  const int h0 = blockIdx.x * 32, d0 = blockIdx.y * 32;
  const int tx = threadIdx.x, ty = threadIdx.y;
#pragma unroll
  for (int i = 0; i < 4; i++)
    t[ty + i * 8][tx] = src[(size_t)(d0 + ty + i * 8) * H_DIM + h0 + tx];
  __syncthreads();
#pragma unroll
  for (int i = 0; i < 4; i++) {
    const int h = h0 + ty + i * 8;      // output row (pre-interleave) == swizzle row mod 8
    const int kd = d0 + tx;             // k index
    const int kpos = (kd & ~63) | ((((kd >> 3) & 7) ^ (h & 7)) << 3) | (kd & 7);
    const unsigned short bv = f2bf(t[tx][ty + i * 8]);
    if (m == 2) {
      wt2[((size_t)e << 20) + ((size_t)h << 10) + kpos] = bv;
    } else {
      const int nc = ((h >> 4) << 5) + (m << 4) + (h & 15);  // interleaved row; nc&7 == h&7
      wt13[((size_t)e << 21) + ((size_t)nc << 10) + kpos] = bv;
    }
  }
}

// ---------------------------------------------------------------------------
// 256x256-tile, BK=64, 8-wave (2Mx4N), 4-phase-per-K-tile schedule with
// counted vmcnt (never 0 in steady state), global_load_lds staging,
// XOR-swizzled LDS reads, setprio around MFMA clusters.
// PH=1: A=xb (perm gather), B=wt13 (N=2048 interleaved) -> act(h1)*h3 -> inner (bf16)
// PH=2: A=inner (compact), B=wt2 (N=1024) -> + b2 -> out (fp32, scatter via perm)
// MFMA operands SWAPPED (mfma(B,A)): acc reg r = output COLUMN quad*4+r,
// output row = lane&15 -> vectorized column-contiguous stores.
// ---------------------------------------------------------------------------
#define MFMA16(d, bb, aa) d = __builtin_amdgcn_mfma_f32_16x16x32_bf16((bb), (aa), (d), 0, 0, 0)

template<int PH>
__global__ __launch_bounds__(512, 2) void mlp_kernel(
    const unsigned short* __restrict__ A,
    const unsigned short* __restrict__ B,
    const float* __restrict__ bA, const float* __restrict__ bB,
    const int* __restrict__ cnt, const int* __restrict__ offs,
    const int* __restrict__ perm,
    unsigned short* __restrict__ inner, float* __restrict__ out)
{
  const int e = blockIdx.z;
  const int ce = cnt[e];
  const int m0 = blockIdx.y * 256;
  if (m0 >= ce) return;
  const int n0 = blockIdx.x * 256;
  const int oe = offs[e];

  __shared__ short smem[65536];   // 128KB: [buf0: A 16K shorts | B 16K][buf1: ...]

  const int tid = threadIdx.x;
  const int wid = tid >> 6, lane = tid & 63;
  const int wm = (wid >> 2) * 128, wn = (wid & 3) * 64;
  const int lr = lane & 15, quad = lane >> 4;
  const int xa = lane & 7;            // == (frag row)&7 for all frag reads
  const int sl = lane >> 3, sc = lane & 7;   // staging: row-in-slot, chunk

  // per-lane staging source offsets (elements) + wave-uniform LDS bases.
  // half h in {0,1} covers tile rows [h*128, h*128+128); wave stages slots {wid, wid+8}
  // of each half (slot = 8 rows = 1KB per gload).
  unsigned aoff[4], boff[4];
  int ldsA[4], ldsB[4];
#pragma unroll
  for (int h = 0; h < 2; h++)
#pragma unroll
    for (int si = 0; si < 2; si++) {
      const int hs = h * 2 + si;
      const int rowb = h * 128 + (wid + si * 8) * 8;
      const int r = rowb + sl;                    // tile row; r&7 == sl
      unsigned arow;
      if constexpr (PH == 1) {
        arow = (unsigned)perm[e * N_TOK + min(m0 + r, ce - 1)];
      } else {
        arow = (unsigned)(oe + min(m0 + r, ce - 1));
      }
      aoff[hs] = (arow << 10) + (unsigned)((sc ^ sl) << 3);          // A: swizzle at source
      const unsigned brow = (PH == 1 ? ((unsigned)e << 11) : ((unsigned)e << 10))
                          + (unsigned)(n0 + r);
      boff[hs] = (brow << 10) + (unsigned)(sc << 3);                 // B: pre-swizzled, linear
      ldsA[hs] = rowb * 64;
      ldsB[hs] = 16384 + rowb * 64;
    }

  f32x4 acc[8][4];
#pragma unroll
  for (int i = 0; i < 8; i++)
#pragma unroll
    for (int j = 0; j < 4; j++) acc[i][j] = (f32x4){0.f, 0.f, 0.f, 0.f};

#define ISSA(d, hs, k0) gload16(A + aoff[hs] + (k0), &smem[(d) * 32768 + ldsA[hs]])
#define ISSB(d, hs, k0) gload16(B + boff[hs] + (k0), &smem[(d) * 32768 + ldsB[hs]])
  // frag reads: logical chunk (kx*4+quad) at swizzled position ^xa; row&7 == xa.
#define LDA_(mi, kx) (*(const bf16x8*)&As[(wm + (mi) * 16 + lr) * 64 + (((((kx) << 2) + quad) ^ xa) << 3)])
#define LDB_(nj, kx) (*(const bf16x8*)&Bs[(wn + (nj) * 16 + lr) * 64 + (((((kx) << 2) + quad) ^ xa) << 3)])

  // ---- prologue: K-tile0 (A+B) -> buf0, K-tile1 B -> buf1. 12 issues/wave.
  ISSA(0, 0, 0);  ISSA(0, 1, 0);  ISSA(0, 2, 0);  ISSA(0, 3, 0);
  ISSB(0, 0, 0);  ISSB(0, 1, 0);  ISSB(0, 2, 0);  ISSB(0, 3, 0);
  ISSB(1, 0, 64); ISSB(1, 1, 64); ISSB(1, 2, 64); ISSB(1, 3, 64);
  asm volatile("s_waitcnt vmcnt(4)" ::: "memory");   // K-tile0 landed; B(t1) in flight
  bar();

  for (int tt = 0; tt < 16; tt++) {
    const int cur = tt & 1, nxt = cur ^ 1;
    const short* As = smem + cur * 32768;
    const short* Bs = As + 16384;
    const int k1 = (tt + 1) << 6, k2 = (tt + 2) << 6;
    bf16x8 a0[4][2], a1[4][2], bfr[4][2];

    // ---- phase 0: read A m0-3 + B n0-1 (12 ds_read); issue A half0(t+1)
#pragma unroll
    for (int mi = 0; mi < 4; mi++) { a0[mi][0] = LDA_(mi, 0); a0[mi][1] = LDA_(mi, 1); }
#pragma unroll
    for (int nj = 0; nj < 2; nj++) { bfr[nj][0] = LDB_(nj, 0); bfr[nj][1] = LDB_(nj, 1); }
    if (tt < 15) { ISSA(nxt, 0, k1); ISSA(nxt, 1, k1); }
    bar();
    __builtin_amdgcn_s_setprio(1);
#pragma unroll
    for (int mi = 0; mi < 4; mi++)
#pragma unroll
      for (int nj = 0; nj < 2; nj++) {
        MFMA16(acc[mi][nj], bfr[nj][0], a0[mi][0]);
        MFMA16(acc[mi][nj], bfr[nj][1], a0[mi][1]);
      }
    __builtin_amdgcn_s_setprio(0);
    bar();

    // ---- phase 1: read B n2-3 (4); issue A half1(t+1). B-LDS last read here.
#pragma unroll
    for (int nj = 2; nj < 4; nj++) { bfr[nj][0] = LDB_(nj, 0); bfr[nj][1] = LDB_(nj, 1); }
    if (tt < 15) { ISSA(nxt, 2, k1); ISSA(nxt, 3, k1); }
    bar();
    __builtin_amdgcn_s_setprio(1);
#pragma unroll
    for (int mi = 0; mi < 4; mi++)
#pragma unroll
      for (int nj = 2; nj < 4; nj++) {
        MFMA16(acc[mi][nj], bfr[nj][0], a0[mi][0]);
        MFMA16(acc[mi][nj], bfr[nj][1], a0[mi][1]);
      }
    __builtin_amdgcn_s_setprio(0);
    bar();

    // ---- phase 2: read A m4-7 (8); issue B half0(t+2) into CURRENT buf
    // (safe: all B reads of this buf certified complete at phase-1 end barrier)
#pragma unroll
    for (int mi = 0; mi < 4; mi++) { a1[mi][0] = LDA_(mi + 4, 0); a1[mi][1] = LDA_(mi + 4, 1); }
    if (tt < 14) { ISSB(cur, 0, k2); ISSB(cur, 1, k2); }
    bar();
    __builtin_amdgcn_s_setprio(1);
#pragma unroll
    for (int mi = 0; mi < 4; mi++)
#pragma unroll
      for (int nj = 0; nj < 2; nj++) {
        MFMA16(acc[mi + 4][nj], bfr[nj][0], a1[mi][0]);
        MFMA16(acc[mi + 4][nj], bfr[nj][1], a1[mi][1]);
      }
    __builtin_amdgcn_s_setprio(0);
    bar();

    // ---- phase 3: issue B half1(t+2); MFMA from regs; boundary wait.
    if (tt < 14) { ISSB(cur, 2, k2); ISSB(cur, 3, k2); }
    __builtin_amdgcn_s_setprio(1);
#pragma unroll
    for (int mi = 0; mi < 4; mi++)
#pragma unroll
      for (int nj = 2; nj < 4; nj++) {
        MFMA16(acc[mi + 4][nj], bfr[nj][0], a1[mi][0]);
        MFMA16(acc[mi + 4][nj], bfr[nj][1], a1[mi][1]);
      }
    __builtin_amdgcn_s_setprio(0);
    // steady state: 12 outstanding -> wait to 4 (= B(t+2)); A(t+1),B(t+1) landed.
    if (tt < 14)      asm volatile("s_waitcnt vmcnt(4)" ::: "memory");
    else if (tt < 15) asm volatile("s_waitcnt vmcnt(0)" ::: "memory");
    if (tt < 15) bar();
  }

#undef ISSA
#undef ISSB
#undef LDA_
#undef LDB_

  // ---- epilogue: acc[mi][nj][r]: row = wm+mi*16+lr, col = wn+nj*16+quad*4+r
  if constexpr (PH == 1) {
    // interleaved N: nj pairs (2p, 2p+1) = (W1, W3) of the same 16 actual cols
    const int colg = (((n0 + wn) >> 5) << 4) + quad * 4;
#pragma unroll
    for (int p = 0; p < 2; p++) {
      const int colb = colg + p * 16;
      const float4 v1 = *(const float4*)&bA[e * H_DIM + colb];
      const float4 v3 = *(const float4*)&bB[e * H_DIM + colb];
#pragma unroll
      for (int mi = 0; mi < 8; mi++) {
        const int rr = m0 + wm + mi * 16 + lr;
        if (rr < ce) {
          unsigned short sv[4];
#pragma unroll
          for (int r = 0; r < 4; r++) {
            const float h1 = acc[mi][2 * p][r]     + ((const float*)&v1)[r];
            const float h3 = acc[mi][2 * p + 1][r] + ((const float*)&v3)[r];
            float a;
            if (e == 0)      a = h1 / (1.f + expf(-h1));                        // silu
            else if (e == 1) a = 0.5f * h1 * (1.f + erff(h1 * 0.70710678118f)); // exact gelu
            else             a = fmaxf(h1, 0.f);                                 // relu
            sv[r] = f2bf(a * h3);
          }
          *(uint2*)&inner[((size_t)(oe + rr) << 10) + colb] = *(const uint2*)sv;
        }
      }
    }
  } else {
#pragma unroll
    for (int nj = 0; nj < 4; nj++) {
      const int colb = n0 + wn + nj * 16 + quad * 4;
      const float4 v2 = *(const float4*)&bA[e * H_DIM + colb];
#pragma unroll
      for (int mi = 0; mi < 8; mi++) {
        const int rr = m0 + wm + mi * 16 + lr;
        if (rr < ce) {
          const int g = perm[e * N_TOK + rr];
          float4 v;
          v.x = acc[mi][nj][0] + v2.x;
          v.y = acc[mi][nj][1] + v2.y;
          v.z = acc[mi][nj][2] + v2.z;
          v.w = acc[mi][nj][3] + v2.w;
          *(float4*)&out[((size_t)g << 10) + colb] = v;
        }
      }
    }
  }
}

extern "C" void kernel_launch(void* const* d_in, const int* in_sizes, int n_in,
                              void* d_out, int out_size, void* d_ws, size_t ws_size,
                              hipStream_t stream)
{
  const float* x  = (const float*)d_in[0];
  const float* W1 = (const float*)d_in[1];
  const float* b1 = (const float*)d_in[2];
  const float* W2 = (const float*)d_in[3];
  const float* b2 = (const float*)d_in[4];
  const float* W3 = (const float*)d_in[5];
  const float* b3 = (const float*)d_in[6];
  const float* Wg = (const float*)d_in[7];
  const float* bg = (const float*)d_in[8];
  const float* gu = (const float*)d_in[9];
  float* out = (float*)d_out;

  char* ws = (char*)d_ws;
  int* cnt  = (int*)(ws + WS_CNT);
  int* offs = (int*)(ws + WS_OFFS);
  int* perm = (int*)(ws + WS_PERM);
  unsigned short* wt13 = (unsigned short*)(ws + WS_WT13);
  unsigned short* wt2  = (unsigned short*)(ws + WS_WT2);
  unsigned short* xb   = (unsigned short*)(ws + WS_XB);
  unsigned short* inner = (unsigned short*)(ws + WS_INNER);

  init_kernel<<<1, 64, 0, stream>>>(cnt);
  gate_kernel<<<N_TOK / 16, 1024, 0, stream>>>(x, Wg, bg, gu, xb, cnt, perm);
  offs_kernel<<<1, 1, 0, stream>>>(cnt, offs);
  wcvt_kernel<<<dim3(32, 32, 9), dim3(32, 8), 0, stream>>>(W1, W3, W2, wt13, wt2);
  // x-dim = n-tiles (fastest) so concurrent blocks share A panels in L2/L3
  mlp_kernel<1><<<dim3(8, 256, 3), 512, 0, stream>>>(
      xb, wt13, b1, b3, cnt, offs, perm, inner, nullptr);
  mlp_kernel<2><<<dim3(4, 256, 3), 512, 0, stream>>>(
      inner, wt2, b2, nullptr, cnt, offs, perm, nullptr, out);
}

// Round 2
// 1056.264 us; speedup vs baseline: 1.0297x; 1.0297x over previous
//
#include <hip/hip_runtime.h>
#include <math.h>

#define N_TOK 65536
#define H_DIM 1024

typedef __attribute__((ext_vector_type(8))) short bf16x8;
typedef __attribute__((ext_vector_type(4))) float f32x4;

// ---------------- ws layout (bytes) ----------------
static const size_t WS_CNT   = 0;                       // int[4]
static const size_t WS_OFFS  = 64;                      // int[4]
static const size_t WS_PERM  = 128;                     // int[3*N_TOK] = 768KB
static const size_t WS_WT13  = 1ull << 20;              // bf16 [3][2048][1024] = 12MB (W1/W3 16-col interleave, k-chunk pre-swizzled)
static const size_t WS_WT2   = WS_WT13 + 12582912ull;   // bf16 [3][1024][1024] = 6MB (k-chunk pre-swizzled)
static const size_t WS_XB    = 20ull << 20;             // bf16 [N][H] = 128MB (linear)
static const size_t WS_INNER = WS_XB + 134217728ull;    // bf16 [N][H] = 128MB (linear, bucket-compacted)

static __device__ __forceinline__ unsigned short f2bf(float f) {
  union { float f; unsigned int u; } v; v.f = f;
  unsigned int r = v.u + 0x7fffu + ((v.u >> 16) & 1u);
  return (unsigned short)(r >> 16);
}

static __device__ __forceinline__ float fast_exp2(float x) {
  float r; asm("v_exp_f32 %0, %1" : "=v"(r) : "v"(x)); return r;
}
static __device__ __forceinline__ float fast_rcp(float x) {
  float r; asm("v_rcp_f32 %0, %1" : "=v"(r) : "v"(x)); return r;
}

// 16B-per-lane async global->LDS. LDS dest = wave-uniform base + lane*16 (linear).
static __device__ __forceinline__ void gload16(const void* g, void* l) {
  __builtin_amdgcn_global_load_lds(
      (const __attribute__((address_space(1))) unsigned int*)g,
      (__attribute__((address_space(3))) unsigned int*)l, 16, 0, 0);
}

static __device__ __forceinline__ void bar() {
  asm volatile("" ::: "memory");
  __builtin_amdgcn_s_barrier();
  asm volatile("" ::: "memory");
}

__global__ void init_kernel(int* cnt) {
  if (threadIdx.x < 4) cnt[threadIdx.x] = 0;
}

// one wave per row: 3 gate logits + gumbel argmax + x->bf16 conversion.
__global__ __launch_bounds__(1024) void gate_kernel(
    const float* __restrict__ x, const float* __restrict__ Wg,
    const float* __restrict__ bg, const float* __restrict__ gu,
    unsigned short* __restrict__ xb, int* __restrict__ cnt,
    int* __restrict__ perm)
{
  __shared__ float wg[3072];
  __shared__ int bexp[16];
  for (int i = threadIdx.x; i < 3072; i += 1024) wg[i] = Wg[i];
  __syncthreads();
  const int wave = threadIdx.x >> 6;
  const int lane = threadIdx.x & 63;
  const int n0 = blockIdx.x * 16;
  const int n = n0 + wave;
  const float4* xrow = (const float4*)(x + (size_t)n * H_DIM);
  unsigned short* xbrow = xb + (size_t)n * H_DIM;
  float s0 = 0.f, s1 = 0.f, s2 = 0.f;
#pragma unroll
  for (int j = 0; j < 4; j++) {
    float4 v = xrow[j * 64 + lane];
    int d0 = (j * 64 + lane) * 4;
    const float* w = &wg[d0 * 3];
    s0 += v.x * w[0] + v.y * w[3] + v.z * w[6] + v.w * w[9];
    s1 += v.x * w[1] + v.y * w[4] + v.z * w[7] + v.w * w[10];
    s2 += v.x * w[2] + v.y * w[5] + v.z * w[8] + v.w * w[11];
    uint2 p;
    p.x = (unsigned)f2bf(v.x) | ((unsigned)f2bf(v.y) << 16);
    p.y = (unsigned)f2bf(v.z) | ((unsigned)f2bf(v.w) << 16);
    ((uint2*)xbrow)[j * 64 + lane] = p;
  }
#pragma unroll
  for (int o = 32; o; o >>= 1) {
    s0 += __shfl_xor(s0, o);
    s1 += __shfl_xor(s1, o);
    s2 += __shfl_xor(s2, o);
  }
  if (lane == 0) {
    const float* u = gu + (size_t)n * 3;
    float l[3] = { s0 + bg[0], s1 + bg[1], s2 + bg[2] };
    int best = 0; float bs = -1e30f;
#pragma unroll
    for (int e = 0; e < 3; e++) {
      float uc = fminf(fmaxf(u[e], 1e-6f), 1.f - 1e-6f);
      float g = -logf(-logf(uc));
      float s = l[e] + g;
      if (s > bs) { bs = s; best = e; }   // strict > == first-max (jnp.argmax)
    }
    bexp[wave] = best;
  }
  __syncthreads();
  if (threadIdx.x == 0) {
    int lc[3] = {0, 0, 0};
    int lpos[16];
    for (int w = 0; w < 16; w++) lpos[w] = lc[bexp[w]]++;
    int lbase[3];
    for (int e = 0; e < 3; e++)
      lbase[e] = lc[e] ? atomicAdd(&cnt[e], lc[e]) : 0;
    for (int w = 0; w < 16; w++) {
      int e = bexp[w];
      perm[e * N_TOK + lbase[e] + lpos[w]] = n0 + w;
    }
  }
}

__global__ void offs_kernel(const int* __restrict__ cnt, int* __restrict__ offs) {
  offs[0] = 0; offs[1] = cnt[0]; offs[2] = cnt[0] + cnt[1]; offs[3] = N_TOK;
}

// W[e][d][h] fp32 -> bf16, transposed to [row][k], k pre-swizzled in 16B chunks
// (stored[row][kb*64 + c*8 + i] = logical[row][kb*64 + (c ^ (row&7))*8 + i]).
// Rewritten: 32h x 64k tiles, LDS transpose, contiguous uint4 (16B) stores.
// W1/W3 interleave into wt13: 16-col groups alternate W1/W3; nc&7 == h&7.
__global__ __launch_bounds__(256) void wcvt_kernel(
    const float* __restrict__ W1, const float* __restrict__ W3,
    const float* __restrict__ W2,
    unsigned short* __restrict__ wt13, unsigned short* __restrict__ wt2)
{
  const int z = blockIdx.z, e = z / 3, m = z % 3;
  const float* src = (m == 0 ? W1 : (m == 1 ? W3 : W2)) + ((size_t)e << 20);
  __shared__ float t[64][33];
  const int h0 = blockIdx.x * 32, d0 = blockIdx.y * 64;
  const int tid = threadIdx.x;
  const int lh = tid & 31, lk = tid >> 5;   // load: 32 h-cols x 8 k-rows per pass
#pragma unroll
  for (int j = 0; j < 8; j++)
    t[j * 8 + lk][lh] = src[(size_t)(d0 + j * 8 + lk) * H_DIM + h0 + lh];
  __syncthreads();
  const int h_l = tid >> 3, kc = tid & 7;   // store: each thread one 8-elem chunk
  const int h = h0 + h_l;
  unsigned short sv[8];
#pragma unroll
  for (int j = 0; j < 8; j++) sv[j] = f2bf(t[kc * 8 + j][h_l]);
  const int kpos = d0 + ((kc ^ (h & 7)) << 3);
  if (m == 2) {
    *(uint4*)&wt2[((size_t)e << 20) + ((size_t)h << 10) + kpos] = *(const uint4*)sv;
  } else {
    const int nc = ((h >> 4) << 5) + (m << 4) + (h & 15);  // interleaved row; nc&7 == h&7
    *(uint4*)&wt13[((size_t)e << 21) + ((size_t)nc << 10) + kpos] = *(const uint4*)sv;
  }
}

// ---------------------------------------------------------------------------
// 256x256-tile, BK=64, 8-wave (2Mx4N), 4-phase-per-K-tile schedule with
// counted vmcnt (never 0 in steady state), global_load_lds staging,
// XOR-swizzled LDS reads, setprio around MFMA clusters.
// R1 changes: (1) co-XCD block remap — all n-tiles of an m-panel share f%8
// so the gathered A panel is fetched into ONE XCD's L2 instead of 8;
// (2) #pragma unroll 2 (pin code size; keep cur/nxt compile-time);
// (3) kk-outer MFMA order (no back-to-back same-acc dependent MFMAs);
// (4) fast silu epilogue (v_exp_f32 + v_rcp_f32).
// PH=1: A=xb (perm gather), B=wt13 (N=2048 interleaved) -> act(h1)*h3 -> inner
// PH=2: A=inner (compact), B=wt2 (N=1024) -> + b2 -> out (fp32, perm scatter)
// MFMA operands SWAPPED (mfma(B,A)): acc reg r = output COLUMN quad*4+r,
// output row = lane&15 -> vectorized column-contiguous stores.
// ---------------------------------------------------------------------------
#define MFMA16(d, bb, aa) d = __builtin_amdgcn_mfma_f32_16x16x32_bf16((bb), (aa), (d), 0, 0, 0)

template<int PH>
__global__ __launch_bounds__(512, 2) void mlp_kernel(
    const unsigned short* __restrict__ A,
    const unsigned short* __restrict__ B,
    const float* __restrict__ bA, const float* __restrict__ bB,
    const int* __restrict__ cnt, const int* __restrict__ offs,
    const int* __restrict__ perm,
    unsigned short* __restrict__ inner, float* __restrict__ out)
{
  constexpr int NXT = (PH == 1) ? 8 : 4;   // n-tiles (== gridDim.x)
  const int e = blockIdx.z;
  const int ce = cnt[e];
  // co-XCD remap: flat id f (per z-slice); all n-tiles of an m-panel have
  // identical f%8 -> same XCD (round-robin dispatch) -> A panel L2-shared.
  const int f = blockIdx.x + NXT * blockIdx.y;
  const int mt = (f & 7) + 8 * ((f >> 3) / NXT);
  const int nt = (f >> 3) % NXT;
  const int m0 = mt << 8;
  if (m0 >= ce) return;
  const int n0 = nt << 8;
  const int oe = offs[e];

  __shared__ short smem[65536];   // 128KB: [buf0: A 16K shorts | B 16K][buf1: ...]

  const int tid = threadIdx.x;
  const int wid = tid >> 6, lane = tid & 63;
  const int wm = (wid >> 2) * 128, wn = (wid & 3) * 64;
  const int lr = lane & 15, quad = lane >> 4;
  const int xa = lane & 7;            // == (frag row)&7 for all frag reads
  const int sl = lane >> 3, sc = lane & 7;   // staging: row-in-slot, chunk

  // per-lane staging source offsets (elements) + wave-uniform LDS bases.
  unsigned aoff[4], boff[4];
  int ldsA[4], ldsB[4];
#pragma unroll
  for (int h = 0; h < 2; h++)
#pragma unroll
    for (int si = 0; si < 2; si++) {
      const int hs = h * 2 + si;
      const int rowb = h * 128 + (wid + si * 8) * 8;
      const int r = rowb + sl;                    // tile row; r&7 == sl
      unsigned arow;
      if constexpr (PH == 1) {
        arow = (unsigned)perm[e * N_TOK + min(m0 + r, ce - 1)];
      } else {
        arow = (unsigned)(oe + min(m0 + r, ce - 1));
      }
      aoff[hs] = (arow << 10) + (unsigned)((sc ^ sl) << 3);          // A: swizzle at source
      const unsigned brow = (PH == 1 ? ((unsigned)e << 11) : ((unsigned)e << 10))
                          + (unsigned)(n0 + r);
      boff[hs] = (brow << 10) + (unsigned)(sc << 3);                 // B: pre-swizzled, linear
      ldsA[hs] = rowb * 64;
      ldsB[hs] = 16384 + rowb * 64;
    }

  f32x4 acc[8][4];
#pragma unroll
  for (int i = 0; i < 8; i++)
#pragma unroll
    for (int j = 0; j < 4; j++) acc[i][j] = (f32x4){0.f, 0.f, 0.f, 0.f};

#define ISSA(d, hs, k0) gload16(A + aoff[hs] + (k0), &smem[(d) * 32768 + ldsA[hs]])
#define ISSB(d, hs, k0) gload16(B + boff[hs] + (k0), &smem[(d) * 32768 + ldsB[hs]])
  // frag reads: logical chunk (kx*4+quad) at swizzled position ^xa; row&7 == xa.
#define LDA_(mi, kx) (*(const bf16x8*)&As[(wm + (mi) * 16 + lr) * 64 + (((((kx) << 2) + quad) ^ xa) << 3)])
#define LDB_(nj, kx) (*(const bf16x8*)&Bs[(wn + (nj) * 16 + lr) * 64 + (((((kx) << 2) + quad) ^ xa) << 3)])

  // ---- prologue: K-tile0 (A+B) -> buf0, K-tile1 B -> buf1. 12 issues/wave.
  ISSA(0, 0, 0);  ISSA(0, 1, 0);  ISSA(0, 2, 0);  ISSA(0, 3, 0);
  ISSB(0, 0, 0);  ISSB(0, 1, 0);  ISSB(0, 2, 0);  ISSB(0, 3, 0);
  ISSB(1, 0, 64); ISSB(1, 1, 64); ISSB(1, 2, 64); ISSB(1, 3, 64);
  asm volatile("s_waitcnt vmcnt(4)" ::: "memory");   // K-tile0 landed; B(t1) in flight
  bar();

#pragma unroll 2
  for (int tt = 0; tt < 16; tt++) {
    const int cur = tt & 1, nxt = cur ^ 1;
    const short* As = smem + cur * 32768;
    const short* Bs = As + 16384;
    const int k1 = (tt + 1) << 6, k2 = (tt + 2) << 6;
    bf16x8 a0[4][2], a1[4][2], bfr[4][2];

    // ---- phase 0: read A m0-3 + B n0-1 (12 ds_read); issue A half0(t+1)
#pragma unroll
    for (int mi = 0; mi < 4; mi++) { a0[mi][0] = LDA_(mi, 0); a0[mi][1] = LDA_(mi, 1); }
#pragma unroll
    for (int nj = 0; nj < 2; nj++) { bfr[nj][0] = LDB_(nj, 0); bfr[nj][1] = LDB_(nj, 1); }
    if (tt < 15) { ISSA(nxt, 0, k1); ISSA(nxt, 1, k1); }
    bar();
    __builtin_amdgcn_s_setprio(1);
#pragma unroll
    for (int kk = 0; kk < 2; kk++)
#pragma unroll
      for (int mi = 0; mi < 4; mi++)
#pragma unroll
        for (int nj = 0; nj < 2; nj++)
          MFMA16(acc[mi][nj], bfr[nj][kk], a0[mi][kk]);
    __builtin_amdgcn_s_setprio(0);
    bar();

    // ---- phase 1: read B n2-3 (4); issue A half1(t+1). B-LDS last read here.
#pragma unroll
    for (int nj = 2; nj < 4; nj++) { bfr[nj][0] = LDB_(nj, 0); bfr[nj][1] = LDB_(nj, 1); }
    if (tt < 15) { ISSA(nxt, 2, k1); ISSA(nxt, 3, k1); }
    bar();
    __builtin_amdgcn_s_setprio(1);
#pragma unroll
    for (int kk = 0; kk < 2; kk++)
#pragma unroll
      for (int mi = 0; mi < 4; mi++)
#pragma unroll
        for (int nj = 2; nj < 4; nj++)
          MFMA16(acc[mi][nj], bfr[nj][kk], a0[mi][kk]);
    __builtin_amdgcn_s_setprio(0);
    bar();

    // ---- phase 2: read A m4-7 (8); issue B half0(t+2) into CURRENT buf
    // (safe: all B reads of this buf certified complete at phase-1 end barrier)
#pragma unroll
    for (int mi = 0; mi < 4; mi++) { a1[mi][0] = LDA_(mi + 4, 0); a1[mi][1] = LDA_(mi + 4, 1); }
    if (tt < 14) { ISSB(cur, 0, k2); ISSB(cur, 1, k2); }
    bar();
    __builtin_amdgcn_s_setprio(1);
#pragma unroll
    for (int kk = 0; kk < 2; kk++)
#pragma unroll
      for (int mi = 0; mi < 4; mi++)
#pragma unroll
        for (int nj = 0; nj < 2; nj++)
          MFMA16(acc[mi + 4][nj], bfr[nj][kk], a1[mi][kk]);
    __builtin_amdgcn_s_setprio(0);
    bar();

    // ---- phase 3: issue B half1(t+2); MFMA from regs; boundary wait.
    if (tt < 14) { ISSB(cur, 2, k2); ISSB(cur, 3, k2); }
    __builtin_amdgcn_s_setprio(1);
#pragma unroll
    for (int kk = 0; kk < 2; kk++)
#pragma unroll
      for (int mi = 0; mi < 4; mi++)
#pragma unroll
        for (int nj = 2; nj < 4; nj++)
          MFMA16(acc[mi + 4][nj], bfr[nj][kk], a1[mi][kk]);
    __builtin_amdgcn_s_setprio(0);
    // steady state: 12 outstanding -> wait to 4 (= B(t+2)); A(t+1),B(t+1) landed.
    if (tt < 14)      asm volatile("s_waitcnt vmcnt(4)" ::: "memory");
    else if (tt < 15) asm volatile("s_waitcnt vmcnt(0)" ::: "memory");
    if (tt < 15) bar();
  }

#undef ISSA
#undef ISSB
#undef LDA_
#undef LDB_

  // ---- epilogue: acc[mi][nj][r]: row = wm+mi*16+lr, col = wn+nj*16+quad*4+r
  if constexpr (PH == 1) {
    // interleaved N: nj pairs (2p, 2p+1) = (W1, W3) of the same 16 actual cols
    const int colg = (((n0 + wn) >> 5) << 4) + quad * 4;
#pragma unroll
    for (int p = 0; p < 2; p++) {
      const int colb = colg + p * 16;
      const float4 v1 = *(const float4*)&bA[e * H_DIM + colb];
      const float4 v3 = *(const float4*)&bB[e * H_DIM + colb];
#pragma unroll
      for (int mi = 0; mi < 8; mi++) {
        const int rr = m0 + wm + mi * 16 + lr;
        if (rr < ce) {
          unsigned short sv[4];
#pragma unroll
          for (int r = 0; r < 4; r++) {
            const float h1 = acc[mi][2 * p][r]     + ((const float*)&v1)[r];
            const float h3 = acc[mi][2 * p + 1][r] + ((const float*)&v3)[r];
            float a;
            if (e == 0)      a = h1 * fast_rcp(1.f + fast_exp2(h1 * -1.44269504f)); // silu
            else if (e == 1) a = 0.5f * h1 * (1.f + erff(h1 * 0.70710678118f));     // exact gelu
            else             a = fmaxf(h1, 0.f);                                     // relu
            sv[r] = f2bf(a * h3);
          }
          *(uint2*)&inner[((size_t)(oe + rr) << 10) + colb] = *(const uint2*)sv;
        }
      }
    }
  } else {
#pragma unroll
    for (int nj = 0; nj < 4; nj++) {
      const int colb = n0 + wn + nj * 16 + quad * 4;
      const float4 v2 = *(const float4*)&bA[e * H_DIM + colb];
#pragma unroll
      for (int mi = 0; mi < 8; mi++) {
        const int rr = m0 + wm + mi * 16 + lr;
        if (rr < ce) {
          const int g = perm[e * N_TOK + rr];
          float4 v;
          v.x = acc[mi][nj][0] + v2.x;
          v.y = acc[mi][nj][1] + v2.y;
          v.z = acc[mi][nj][2] + v2.z;
          v.w = acc[mi][nj][3] + v2.w;
          *(float4*)&out[((size_t)g << 10) + colb] = v;
        }
      }
    }
  }
}

extern "C" void kernel_launch(void* const* d_in, const int* in_sizes, int n_in,
                              void* d_out, int out_size, void* d_ws, size_t ws_size,
                              hipStream_t stream)
{
  const float* x  = (const float*)d_in[0];
  const float* W1 = (const float*)d_in[1];
  const float* b1 = (const float*)d_in[2];
  const float* W2 = (const float*)d_in[3];
  const float* b2 = (const float*)d_in[4];
  const float* W3 = (const float*)d_in[5];
  const float* b3 = (const float*)d_in[6];
  const float* Wg = (const float*)d_in[7];
  const float* bg = (const float*)d_in[8];
  const float* gu = (const float*)d_in[9];
  float* out = (float*)d_out;

  char* ws = (char*)d_ws;
  int* cnt  = (int*)(ws + WS_CNT);
  int* offs = (int*)(ws + WS_OFFS);
  int* perm = (int*)(ws + WS_PERM);
  unsigned short* wt13 = (unsigned short*)(ws + WS_WT13);
  unsigned short* wt2  = (unsigned short*)(ws + WS_WT2);
  unsigned short* xb   = (unsigned short*)(ws + WS_XB);
  unsigned short* inner = (unsigned short*)(ws + WS_INNER);

  init_kernel<<<1, 64, 0, stream>>>(cnt);
  gate_kernel<<<N_TOK / 16, 1024, 0, stream>>>(x, Wg, bg, gu, xb, cnt, perm);
  offs_kernel<<<1, 1, 0, stream>>>(cnt, offs);
  wcvt_kernel<<<dim3(32, 16, 9), 256, 0, stream>>>(W1, W3, W2, wt13, wt2);
  mlp_kernel<1><<<dim3(8, 256, 3), 512, 0, stream>>>(
      xb, wt13, b1, b3, cnt, offs, perm, inner, nullptr);
  mlp_kernel<2><<<dim3(4, 256, 3), 512, 0, stream>>>(
      inner, wt2, b2, nullptr, cnt, offs, perm, nullptr, out);
}